// Round 6
// baseline (1103.004 us; speedup 1.0000x reference)
//
#include <hip/hip_runtime.h>
#include <cstdint>
#include <math.h>

// EnergyCAModel: 4-step neural CA.
// x [B=16,H=128,W=128,C=16] f32. Out = x_steps [4*16*128*128*16] ++ fr_steps [4*16*128*128].
#define HW2    16384      // 128*128
#define BHW    262144     // 16*128*128
#define XSLICE 4194304    // BHW*16

__host__ __device__ static inline uint32_t rotl32(uint32_t v, int r) {
  return (v << r) | (v >> (32 - r));
}

// Exact JAX Threefry-2x32 (20 rounds), partitionable layout (verified R1).
__host__ __device__ static inline void tf2x32(uint32_t k0, uint32_t k1,
                                              uint32_t x0, uint32_t x1,
                                              uint32_t& o0, uint32_t& o1) {
  uint32_t ks2 = k0 ^ k1 ^ 0x1BD11BDAu;
  x0 += k0; x1 += k1;
#define TFR(r) { x0 += x1; x1 = rotl32(x1, (r)); x1 ^= x0; }
  TFR(13) TFR(15) TFR(26) TFR(6)   x0 += k1;  x1 += ks2 + 1u;
  TFR(17) TFR(29) TFR(16) TFR(24)  x0 += ks2; x1 += k0 + 2u;
  TFR(13) TFR(15) TFR(26) TFR(6)   x0 += k0;  x1 += k1 + 3u;
  TFR(17) TFR(29) TFR(16) TFR(24)  x0 += k1;  x1 += ks2 + 4u;
  TFR(13) TFR(15) TFR(26) TFR(6)   x0 += ks2; x1 += k0 + 5u;
#undef TFR
  o0 = x0; o1 = x1;
}

__device__ static inline float bits_to_unit(uint32_t bits) {
  return __uint_as_float((bits >> 9) | 0x3f800000u) - 1.0f;  // [0,1)
}

__device__ static inline uint32_t rng_bits(uint32_t sk0, uint32_t sk1, uint32_t f) {
  uint32_t o0, o1;
  tf2x32(sk0, sk1, 0u, f, o0, o1);
  return o0 ^ o1;
}

__device__ static inline float sigmoidf_(float z) {
  if (z >= 0.f) { float e = expf(-z); return 1.f / (1.f + e); }
  float e = expf(z); return e / (1.f + e);
}

// Sobel features + pre-alive max for one pixel.
__device__ static inline void sobel_feat(const float* __restrict__ base,
                                         int hh, int ww, float* dxv, float& m3) {
#pragma unroll
  for (int c = 0; c < 48; ++c) dxv[c] = 0.f;
  m3 = -INFINITY;
#pragma unroll
  for (int dh = -1; dh <= 1; ++dh) {
    const int j = dh + 1;
    const int h2 = hh + dh;
    const bool hok = ((unsigned)h2 < 128u);
#pragma unroll
    for (int dw = -1; dw <= 1; ++dw) {
      const int i = dw + 1;
      const int w2 = ww + dw;
      float v[16];
      if (hok && ((unsigned)w2 < 128u)) {
        const float* s = base + (((h2 << 7) + w2) << 4);
#pragma unroll
        for (int c = 0; c < 16; c += 4) {
          float4 q = *(const float4*)(s + c);
          v[c] = q.x; v[c + 1] = q.y; v[c + 2] = q.z; v[c + 3] = q.w;
        }
        m3 = fmaxf(m3, v[3]);
      } else {
#pragma unroll
        for (int c = 0; c < 16; ++c) v[c] = 0.f;
      }
      const float smv[3] = {1.f, 2.f, 1.f};
      const float dfv[3] = {-1.f, 0.f, 1.f};
      const float c1 = smv[i] * dfv[j] * 0.125f;  // y1
      const float c2 = dfv[i] * smv[j] * 0.125f;  // y2
      if (dh == 0 && dw == 0) {
#pragma unroll
        for (int c = 0; c < 16; ++c) dxv[c] = v[c];
      }
      if (c1 != 0.f) {
#pragma unroll
        for (int c = 0; c < 16; ++c) dxv[16 + c] = fmaf(c1, v[c], dxv[16 + c]);
      }
      if (c2 != 0.f) {
#pragma unroll
        for (int c = 0; c < 16; ++c) dxv[32 + c] = fmaf(c2, v[c], dxv[32 + c]);
      }
    }
  }
}

// Kernel A: 4 pixels/thread (P=4). LDS-broadcast weight delivery is charged
// per-lane (R3/R5-validated: 17 ops ~ 198 LDS-pipe cyc/jj/wave, one pipe/CU),
// so pixels-per-thread is the only amortizer: LDS time = (16/P waves/CU)
// x 256jj x 198cyc -> 84us at P=4. VGPR ~320 -> 1 block/CU (launch_bounds 256,1).
// Rows packed [w0(48)|w1t(16)|b0|pad3] = 68 floats; two 128-row passes (34.8KB).
__global__ __launch_bounds__(256, 1) void ca_step_a(
    const float* __restrict__ xin,   // [B,H,W,16]
    const float* __restrict__ w0g,   // [256,48]
    const float* __restrict__ w1pg,  // [256,20] packed (w1t(16)|b0|pad3) in ws
    const float* __restrict__ wfrg,  // [48]
    float* __restrict__ xmid,
    float* __restrict__ ch3,
    float* __restrict__ premask,
    float* __restrict__ frout,
    uint32_t sk0, uint32_t sk1) {
  __shared__ float sw[128 * 68];   // 34.8 KB

  const int tid = threadIdx.x;
  const int p0  = blockIdx.x * 1024 + tid;   // +256*i for i=0..3
  const int b   = p0 >> 14;
  const int rem = p0 & 16383;
  const int hh0 = rem >> 7;
  const int ww0 = rem & 127;

  const float* base = xin + ((size_t)b << 18);

  float dx0[48], dx1[48], dx2[48], dx3[48];
  float m30, m31, m32, m33;
  sobel_feat(base, hh0,     ww0, dx0, m30);
  sobel_feat(base, hh0 + 2, ww0, dx1, m31);
  sobel_feat(base, hh0 + 4, ww0, dx2, m32);
  sobel_feat(base, hh0 + 6, ww0, dx3, m33);

  const bool pre0 = (m30 > 0.1f);
  const bool pre1 = (m31 > 0.1f);
  const bool pre2 = (m32 > 0.1f);
  const bool pre3 = (m33 > 0.1f);

  float z0 = 0.f, z1 = 0.f, z2 = 0.f, z3 = 0.f;
#pragma unroll
  for (int c = 0; c < 48; ++c) {
    const float wf = wfrg[c];
    z0 = fmaf(dx0[c], wf, z0);
    z1 = fmaf(dx1[c], wf, z1);
    z2 = fmaf(dx2[c], wf, z2);
    z3 = fmaf(dx3[c], wf, z3);
  }
  const float fr0 = pre0 ? sigmoidf_(z0) : 0.f;
  const float fr1 = pre1 ? sigmoidf_(z1) : 0.f;
  const float fr2 = pre2 ? sigmoidf_(z2) : 0.f;
  const float fr3 = pre3 ? sigmoidf_(z3) : 0.f;

#define GATE(FR, P, OUT)                                                       \
  {                                                                            \
    const float u0 = bits_to_unit(rng_bits(sk0, sk1, 2u * (uint32_t)(P)));     \
    const float u1 = bits_to_unit(rng_bits(sk0, sk1, 2u * (uint32_t)(P) + 1u));\
    const float d0 = logf((FR) + 1e-10f) - logf(-logf(u0 + 1e-20f) + 1e-20f);  \
    const float d1 = logf(1.0f - (FR) + 1e-10f) - logf(-logf(u1 + 1e-20f) + 1e-20f); \
    OUT = (d0 >= d1) ? 1.f : 0.f;                                              \
  }
  float upd0, upd1, upd2, upd3;
  GATE(fr0, p0,        upd0)
  GATE(fr1, p0 + 256,  upd1)
  GATE(fr2, p0 + 512,  upd2)
  GATE(fr3, p0 + 768,  upd3)
#undef GATE

  float h0[16], h1[16], h2[16], h3[16];
#pragma unroll
  for (int c = 0; c < 16; ++c) { h0[c] = 0.f; h1[c] = 0.f; h2[c] = 0.f; h3[c] = 0.f; }

  for (int pass = 0; pass < 2; ++pass) {
    const int jb = pass << 7;
    if (pass) __syncthreads();  // previous pass fully consumed
    {
      const float4* w04  = (const float4*)w0g;
      const float4* w1p4 = (const float4*)w1pg;
      float4* sw4 = (float4*)sw;
      for (int i = tid; i < 2176; i += 256) {   // 128 rows x 17 float4
        const int j = i / 17, q = i - j * 17;
        sw4[i] = (q < 12) ? w04[(jb + j) * 12 + q]
                          : w1p4[(jb + j) * 5 + (q - 12)];
      }
    }
    __syncthreads();
#pragma unroll 2
    for (int jj = 0; jj < 128; ++jj) {
      const float* row = sw + jj * 68;
      float a00 = 0.f, a01 = 0.f, a10 = 0.f, a11 = 0.f;
      float a20 = 0.f, a21 = 0.f, a30 = 0.f, a31 = 0.f;
#pragma unroll
      for (int ks = 0; ks < 6; ++ks) {
        const int k = ks * 8;
        const float4 wa = *(const float4*)(row + k);
        const float4 wb = *(const float4*)(row + k + 4);
        a00 = fmaf(wa.x, dx0[k + 0], a00); a01 = fmaf(wa.y, dx0[k + 1], a01);
        a00 = fmaf(wa.z, dx0[k + 2], a00); a01 = fmaf(wa.w, dx0[k + 3], a01);
        a00 = fmaf(wb.x, dx0[k + 4], a00); a01 = fmaf(wb.y, dx0[k + 5], a01);
        a00 = fmaf(wb.z, dx0[k + 6], a00); a01 = fmaf(wb.w, dx0[k + 7], a01);
        a10 = fmaf(wa.x, dx1[k + 0], a10); a11 = fmaf(wa.y, dx1[k + 1], a11);
        a10 = fmaf(wa.z, dx1[k + 2], a10); a11 = fmaf(wa.w, dx1[k + 3], a11);
        a10 = fmaf(wb.x, dx1[k + 4], a10); a11 = fmaf(wb.y, dx1[k + 5], a11);
        a10 = fmaf(wb.z, dx1[k + 6], a10); a11 = fmaf(wb.w, dx1[k + 7], a11);
        a20 = fmaf(wa.x, dx2[k + 0], a20); a21 = fmaf(wa.y, dx2[k + 1], a21);
        a20 = fmaf(wa.z, dx2[k + 2], a20); a21 = fmaf(wa.w, dx2[k + 3], a21);
        a20 = fmaf(wb.x, dx2[k + 4], a20); a21 = fmaf(wb.y, dx2[k + 5], a21);
        a20 = fmaf(wb.z, dx2[k + 6], a20); a21 = fmaf(wb.w, dx2[k + 7], a21);
        a30 = fmaf(wa.x, dx3[k + 0], a30); a31 = fmaf(wa.y, dx3[k + 1], a31);
        a30 = fmaf(wa.z, dx3[k + 2], a30); a31 = fmaf(wa.w, dx3[k + 3], a31);
        a30 = fmaf(wb.x, dx3[k + 4], a30); a31 = fmaf(wb.y, dx3[k + 5], a31);
        a30 = fmaf(wb.z, dx3[k + 6], a30); a31 = fmaf(wb.w, dx3[k + 7], a31);
      }
      const float bb = row[64];
      const float r0 = fmaxf(bb + (a00 + a01), 0.f);
      const float r1 = fmaxf(bb + (a10 + a11), 0.f);
      const float r2 = fmaxf(bb + (a20 + a21), 0.f);
      const float r3 = fmaxf(bb + (a30 + a31), 0.f);
#pragma unroll
      for (int c4 = 0; c4 < 4; ++c4) {
        const float4 q = *(const float4*)(row + 48 + (c4 << 2));
        const int c = c4 << 2;
        h0[c]     = fmaf(q.x, r0, h0[c]);     h1[c]     = fmaf(q.x, r1, h1[c]);
        h0[c + 1] = fmaf(q.y, r0, h0[c + 1]); h1[c + 1] = fmaf(q.y, r1, h1[c + 1]);
        h0[c + 2] = fmaf(q.z, r0, h0[c + 2]); h1[c + 2] = fmaf(q.z, r1, h1[c + 2]);
        h0[c + 3] = fmaf(q.w, r0, h0[c + 3]); h1[c + 3] = fmaf(q.w, r1, h1[c + 3]);
        h2[c]     = fmaf(q.x, r2, h2[c]);     h3[c]     = fmaf(q.x, r3, h3[c]);
        h2[c + 1] = fmaf(q.y, r2, h2[c + 1]); h3[c + 1] = fmaf(q.y, r3, h3[c + 1]);
        h2[c + 2] = fmaf(q.z, r2, h2[c + 2]); h3[c + 2] = fmaf(q.z, r3, h3[c + 2]);
        h2[c + 3] = fmaf(q.w, r2, h2[c + 3]); h3[c + 3] = fmaf(q.w, r3, h3[c + 3]);
      }
    }
  }

#define EPILOG(PX, DX, H, UPD, PRE, FR)                                        \
  {                                                                            \
    float* dst = xmid + ((size_t)(PX) << 4);                                   \
    _Pragma("unroll")                                                          \
    for (int c = 0; c < 16; c += 4) {                                          \
      float4 q;                                                                \
      q.x = fmaf(UPD, H[c],     DX[c]);                                        \
      q.y = fmaf(UPD, H[c + 1], DX[c + 1]);                                    \
      q.z = fmaf(UPD, H[c + 2], DX[c + 2]);                                    \
      q.w = fmaf(UPD, H[c + 3], DX[c + 3]);                                    \
      *(float4*)(dst + c) = q;                                                 \
    }                                                                          \
    ch3[PX]     = fmaf(UPD, H[3], DX[3]);                                      \
    premask[PX] = (PRE) ? 1.f : 0.f;                                           \
    frout[PX]   = FR;                                                          \
  }
  EPILOG(p0,       dx0, h0, upd0, pre0, fr0)
  EPILOG(p0 + 256, dx1, h1, upd1, pre1, fr1)
  EPILOG(p0 + 512, dx2, h2, upd2, pre2, fr2)
  EPILOG(p0 + 768, dx3, h3, upd3, pre3, fr3)
#undef EPILOG
}

// Kernel B: post-alive mask; zero dead pixels in-place in the d_out slice.
__global__ __launch_bounds__(256) void ca_step_b(
    float* __restrict__ xs, const float* __restrict__ ch3,
    const float* __restrict__ premask) {
  const int p   = blockIdx.x * 256 + threadIdx.x;
  const int b   = p >> 14;
  const int rem = p & 16383;
  const int hh  = rem >> 7;
  const int ww  = rem & 127;
  const float* cb = ch3 + (b << 14);
  float m = -INFINITY;
#pragma unroll
  for (int dh = -1; dh <= 1; ++dh) {
    const int h2 = hh + dh;
    if ((unsigned)h2 >= 128u) continue;
#pragma unroll
    for (int dw = -1; dw <= 1; ++dw) {
      const int w2 = ww + dw;
      if ((unsigned)w2 >= 128u) continue;
      m = fmaxf(m, cb[(h2 << 7) + w2]);
    }
  }
  const bool alive = (premask[p] != 0.f) && (m > 0.1f);
  if (!alive) {
    float4 z; z.x = 0.f; z.y = 0.f; z.z = 0.f; z.w = 0.f;
    float* dst = xs + ((size_t)p << 4);
    *(float4*)(dst)      = z;
    *(float4*)(dst + 4)  = z;
    *(float4*)(dst + 8)  = z;
    *(float4*)(dst + 12) = z;
  }
}

// Pack w1 (transposed) + b0 into [256][20] rows: [w1t(16) | b0 | pad3].
__global__ void pack_w1(const float* __restrict__ w1, const float* __restrict__ b0,
                        float* __restrict__ w1p) {
  const int j = blockIdx.x * 256 + threadIdx.x;
  if (j < 256) {
#pragma unroll
    for (int c = 0; c < 16; ++c) w1p[j * 20 + c] = w1[c * 256 + j];
    w1p[j * 20 + 16] = b0[j];
    w1p[j * 20 + 17] = 0.f;
    w1p[j * 20 + 18] = 0.f;
    w1p[j * 20 + 19] = 0.f;
  }
}

extern "C" void kernel_launch(void* const* d_in, const int* in_sizes, int n_in,
                              void* d_out, int out_size, void* d_ws, size_t ws_size,
                              hipStream_t stream) {
  const float* x0  = (const float*)d_in[0];
  const float* w0  = (const float*)d_in[1];
  const float* b0  = (const float*)d_in[2];
  const float* w1  = (const float*)d_in[3];
  const float* wfr = (const float*)d_in[4];
  const int steps = 4;

  float* xsteps  = (float*)d_out;
  float* frsteps = xsteps + (size_t)steps * XSLICE;

  float* w1p = (float*)d_ws;        // 5120 f
  float* ch3 = w1p + 5120;          // BHW f
  float* pre = ch3 + BHW;           // BHW f

  // step keys = jax.random.split(jax.random.key(42), 4) (partitionable threefry)
  uint32_t sk[4][2];
  for (int s = 0; s < steps; ++s)
    tf2x32(0u, 42u, 0u, (uint32_t)s, sk[s][0], sk[s][1]);

  pack_w1<<<1, 256, 0, stream>>>(w1, b0, w1p);
  for (int s = 0; s < steps; ++s) {
    const float* xin = (s == 0) ? x0 : (xsteps + (size_t)(s - 1) * XSLICE);
    float* xmid = xsteps + (size_t)s * XSLICE;
    ca_step_a<<<256, 256, 0, stream>>>(xin, w0, w1p, wfr, xmid, ch3, pre,
                                       frsteps + (size_t)s * BHW, sk[s][0], sk[s][1]);
    ca_step_b<<<1024, 256, 0, stream>>>(xmid, ch3, pre);
  }
}

// Round 7
// 462.797 us; speedup vs baseline: 2.3833x; 2.3833x over previous
//
#include <hip/hip_runtime.h>
#include <cstdint>
#include <math.h>

// EnergyCAModel: 4-step neural CA.
// x [B=16,H=128,W=128,C=16] f32. Out = x_steps [4*16*128*128*16] ++ fr_steps [4*16*128*128].
#define HW2    16384      // 128*128
#define BHW    262144     // 16*128*128
#define XSLICE 4194304    // BHW*16

__host__ __device__ static inline uint32_t rotl32(uint32_t v, int r) {
  return (v << r) | (v >> (32 - r));
}

// Exact JAX Threefry-2x32 (20 rounds), partitionable layout (verified R1).
__host__ __device__ static inline void tf2x32(uint32_t k0, uint32_t k1,
                                              uint32_t x0, uint32_t x1,
                                              uint32_t& o0, uint32_t& o1) {
  uint32_t ks2 = k0 ^ k1 ^ 0x1BD11BDAu;
  x0 += k0; x1 += k1;
#define TFR(r) { x0 += x1; x1 = rotl32(x1, (r)); x1 ^= x0; }
  TFR(13) TFR(15) TFR(26) TFR(6)   x0 += k1;  x1 += ks2 + 1u;
  TFR(17) TFR(29) TFR(16) TFR(24)  x0 += ks2; x1 += k0 + 2u;
  TFR(13) TFR(15) TFR(26) TFR(6)   x0 += k0;  x1 += k1 + 3u;
  TFR(17) TFR(29) TFR(16) TFR(24)  x0 += k1;  x1 += ks2 + 4u;
  TFR(13) TFR(15) TFR(26) TFR(6)   x0 += ks2; x1 += k0 + 5u;
#undef TFR
  o0 = x0; o1 = x1;
}

__device__ static inline float bits_to_unit(uint32_t bits) {
  return __uint_as_float((bits >> 9) | 0x3f800000u) - 1.0f;  // [0,1)
}

__device__ static inline uint32_t rng_bits(uint32_t sk0, uint32_t sk1, uint32_t f) {
  uint32_t o0, o1;
  tf2x32(sk0, sk1, 0u, f, o0, o1);
  return o0 ^ o1;
}

__device__ static inline float sigmoidf_(float z) {
  if (z >= 0.f) { float e = expf(-z); return 1.f / (1.f + e); }
  float e = expf(z); return e / (1.f + e);
}

// Sobel features + pre-alive max for one pixel.
__device__ static inline void sobel_feat(const float* __restrict__ base,
                                         int hh, int ww, float* dxv, float& m3) {
#pragma unroll
  for (int c = 0; c < 48; ++c) dxv[c] = 0.f;
  m3 = -INFINITY;
#pragma unroll
  for (int dh = -1; dh <= 1; ++dh) {
    const int j = dh + 1;
    const int h2 = hh + dh;
    const bool hok = ((unsigned)h2 < 128u);
#pragma unroll
    for (int dw = -1; dw <= 1; ++dw) {
      const int i = dw + 1;
      const int w2 = ww + dw;
      float v[16];
      if (hok && ((unsigned)w2 < 128u)) {
        const float* s = base + (((h2 << 7) + w2) << 4);
#pragma unroll
        for (int c = 0; c < 16; c += 4) {
          float4 q = *(const float4*)(s + c);
          v[c] = q.x; v[c + 1] = q.y; v[c + 2] = q.z; v[c + 3] = q.w;
        }
        m3 = fmaxf(m3, v[3]);
      } else {
#pragma unroll
        for (int c = 0; c < 16; ++c) v[c] = 0.f;
      }
      const float smv[3] = {1.f, 2.f, 1.f};
      const float dfv[3] = {-1.f, 0.f, 1.f};
      const float c1 = smv[i] * dfv[j] * 0.125f;  // y1
      const float c2 = dfv[i] * smv[j] * 0.125f;  // y2
      if (dh == 0 && dw == 0) {
#pragma unroll
        for (int c = 0; c < 16; ++c) dxv[c] = v[c];
      }
      if (c1 != 0.f) {
#pragma unroll
        for (int c = 0; c < 16; ++c) dxv[16 + c] = fmaf(c1, v[c], dxv[16 + c]);
      }
      if (c2 != 0.f) {
#pragma unroll
        for (int c = 0; c < 16; ++c) dxv[32 + c] = fmaf(c2, v[c], dxv[32 + c]);
      }
    }
  }
}

// Kernel A: 2 pixels/thread; SPLIT WEIGHT DELIVERY.
//  - neurons   0..127: rows in LDS, broadcast ds_read (R3 mechanics, 17 ops/jj)
//  - neurons 128..255: rows streamed on the SCALAR pipe (uniform address ->
//    s_load, one 65-float single-buffered row; the L-neuron's ds_read drain
//    covers the SMEM latency; the S-neuron computes purely from SGPRs).
// LDS return-path charge is per-lane-bytes even for broadcast (~12cyc/b128),
// so halving LDS ops per neuron ~doubles the LDS-bound jj-loop throughput.
__global__ __launch_bounds__(256, 2) void ca_step_a(
    const float* __restrict__ xin,   // [B,H,W,16]
    const float* __restrict__ pw,    // [256][68] packed rows: w0(48)|w1t(16)|b0|pad3
    const float* __restrict__ wfrg,  // [48]
    float* __restrict__ xmid,
    float* __restrict__ ch3,
    float* __restrict__ premask,
    float* __restrict__ frout,
    uint32_t sk0, uint32_t sk1) {
  __shared__ float sw[128 * 68];   // 34.8 KB: rows 0..127

  const int tid = threadIdx.x;
  {
    const float4* src = (const float4*)pw;   // rows 0..127 = first 2176 float4
    float4* dst = (float4*)sw;
    for (int i = tid; i < 2176; i += 256) dst[i] = src[i];
  }
  __syncthreads();

  const int p0  = blockIdx.x * 512 + tid;
  const int p1  = p0 + 256;
  const int b   = p0 >> 14;
  const int rem = p0 & 16383;
  const int hh0 = rem >> 7;
  const int ww0 = rem & 127;
  const int hh1 = hh0 + 2;          // p1 = p0 + 256 -> +2 rows

  const float* base = xin + ((size_t)b << 18);

  float dx0[48], dx1[48];
  float m30, m31;
  sobel_feat(base, hh0, ww0, dx0, m30);
  sobel_feat(base, hh1, ww0, dx1, m31);

  const bool pre0 = (m30 > 0.1f);
  const bool pre1 = (m31 > 0.1f);

  float z0 = 0.f, z1 = 0.f;
#pragma unroll
  for (int c = 0; c < 48; ++c) {
    z0 = fmaf(dx0[c], wfrg[c], z0);
    z1 = fmaf(dx1[c], wfrg[c], z1);
  }
  const float fr0 = pre0 ? sigmoidf_(z0) : 0.f;
  const float fr1 = pre1 ? sigmoidf_(z1) : 0.f;

  float upd0, upd1;
  {
    const float u0 = bits_to_unit(rng_bits(sk0, sk1, 2u * (uint32_t)p0));
    const float u1 = bits_to_unit(rng_bits(sk0, sk1, 2u * (uint32_t)p0 + 1u));
    const float d0 = logf(fr0 + 1e-10f) - logf(-logf(u0 + 1e-20f) + 1e-20f);
    const float d1 = logf(1.0f - fr0 + 1e-10f) - logf(-logf(u1 + 1e-20f) + 1e-20f);
    upd0 = (d0 >= d1) ? 1.f : 0.f;
  }
  {
    const float u0 = bits_to_unit(rng_bits(sk0, sk1, 2u * (uint32_t)p1));
    const float u1 = bits_to_unit(rng_bits(sk0, sk1, 2u * (uint32_t)p1 + 1u));
    const float d0 = logf(fr1 + 1e-10f) - logf(-logf(u0 + 1e-20f) + 1e-20f);
    const float d1 = logf(1.0f - fr1 + 1e-10f) - logf(-logf(u1 + 1e-20f) + 1e-20f);
    upd1 = (d0 >= d1) ? 1.f : 0.f;
  }

  float h0[16], h1[16];
#pragma unroll
  for (int c = 0; c < 16; ++c) { h0[c] = 0.f; h1[c] = 0.f; }

  for (int i = 0; i < 128; ++i) {
    // ---- issue scalar row (neuron 128+i) first: uniform -> s_load ----
    const float* __restrict__ srow = pw + (size_t)(128 + i) * 68;
    float S[65];
#pragma unroll
    for (int q = 0; q < 65; ++q) S[q] = srow[q];

    // ---- L-neuron i from LDS (ds_read drain covers the s_load latency) ----
    {
      const float* row = sw + i * 68;
      float a00 = 0.f, a01 = 0.f, a10 = 0.f, a11 = 0.f;
#pragma unroll
      for (int ks = 0; ks < 6; ++ks) {
        const int k = ks * 8;
        const float4 wa = *(const float4*)(row + k);
        const float4 wb = *(const float4*)(row + k + 4);
        a00 = fmaf(wa.x, dx0[k + 0], a00); a01 = fmaf(wa.y, dx0[k + 1], a01);
        a00 = fmaf(wa.z, dx0[k + 2], a00); a01 = fmaf(wa.w, dx0[k + 3], a01);
        a00 = fmaf(wb.x, dx0[k + 4], a00); a01 = fmaf(wb.y, dx0[k + 5], a01);
        a00 = fmaf(wb.z, dx0[k + 6], a00); a01 = fmaf(wb.w, dx0[k + 7], a01);
        a10 = fmaf(wa.x, dx1[k + 0], a10); a11 = fmaf(wa.y, dx1[k + 1], a11);
        a10 = fmaf(wa.z, dx1[k + 2], a10); a11 = fmaf(wa.w, dx1[k + 3], a11);
        a10 = fmaf(wb.x, dx1[k + 4], a10); a11 = fmaf(wb.y, dx1[k + 5], a11);
        a10 = fmaf(wb.z, dx1[k + 6], a10); a11 = fmaf(wb.w, dx1[k + 7], a11);
      }
      const float bb = row[64];
      const float r0 = fmaxf(bb + (a00 + a01), 0.f);
      const float r1 = fmaxf(bb + (a10 + a11), 0.f);
#pragma unroll
      for (int c4 = 0; c4 < 4; ++c4) {
        const float4 q = *(const float4*)(row + 48 + (c4 << 2));
        const int c = c4 << 2;
        h0[c]     = fmaf(q.x, r0, h0[c]);     h1[c]     = fmaf(q.x, r1, h1[c]);
        h0[c + 1] = fmaf(q.y, r0, h0[c + 1]); h1[c + 1] = fmaf(q.y, r1, h1[c + 1]);
        h0[c + 2] = fmaf(q.z, r0, h0[c + 2]); h1[c + 2] = fmaf(q.z, r1, h1[c + 2]);
        h0[c + 3] = fmaf(q.w, r0, h0[c + 3]); h1[c + 3] = fmaf(q.w, r1, h1[c + 3]);
      }
    }

    // ---- S-neuron 128+i from SGPRs (zero LDS traffic) ----
    {
      float a00 = 0.f, a01 = 0.f, a10 = 0.f, a11 = 0.f;
#pragma unroll
      for (int k = 0; k < 48; k += 2) {
        a00 = fmaf(S[k], dx0[k], a00);     a01 = fmaf(S[k + 1], dx0[k + 1], a01);
        a10 = fmaf(S[k], dx1[k], a10);     a11 = fmaf(S[k + 1], dx1[k + 1], a11);
      }
      const float bb = S[64];
      const float r0 = fmaxf(bb + (a00 + a01), 0.f);
      const float r1 = fmaxf(bb + (a10 + a11), 0.f);
#pragma unroll
      for (int c = 0; c < 16; ++c) {
        h0[c] = fmaf(S[48 + c], r0, h0[c]);
        h1[c] = fmaf(S[48 + c], r1, h1[c]);
      }
    }
  }

  float* dst0 = xmid + ((size_t)p0 << 4);
  float* dst1 = xmid + ((size_t)p1 << 4);
#pragma unroll
  for (int c = 0; c < 16; c += 4) {
    float4 q0, q1;
    q0.x = fmaf(upd0, h0[c],     dx0[c]);     q1.x = fmaf(upd1, h1[c],     dx1[c]);
    q0.y = fmaf(upd0, h0[c + 1], dx0[c + 1]); q1.y = fmaf(upd1, h1[c + 1], dx1[c + 1]);
    q0.z = fmaf(upd0, h0[c + 2], dx0[c + 2]); q1.z = fmaf(upd1, h1[c + 2], dx1[c + 2]);
    q0.w = fmaf(upd0, h0[c + 3], dx0[c + 3]); q1.w = fmaf(upd1, h1[c + 3], dx1[c + 3]);
    *(float4*)(dst0 + c) = q0;
    *(float4*)(dst1 + c) = q1;
  }
  ch3[p0]     = fmaf(upd0, h0[3], dx0[3]);
  ch3[p1]     = fmaf(upd1, h1[3], dx1[3]);
  premask[p0] = pre0 ? 1.f : 0.f;
  premask[p1] = pre1 ? 1.f : 0.f;
  frout[p0]   = fr0;
  frout[p1]   = fr1;
}

// Kernel B: post-alive mask; zero dead pixels in-place in the d_out slice.
__global__ __launch_bounds__(256) void ca_step_b(
    float* __restrict__ xs, const float* __restrict__ ch3,
    const float* __restrict__ premask) {
  const int p   = blockIdx.x * 256 + threadIdx.x;
  const int b   = p >> 14;
  const int rem = p & 16383;
  const int hh  = rem >> 7;
  const int ww  = rem & 127;
  const float* cb = ch3 + (b << 14);
  float m = -INFINITY;
#pragma unroll
  for (int dh = -1; dh <= 1; ++dh) {
    const int h2 = hh + dh;
    if ((unsigned)h2 >= 128u) continue;
#pragma unroll
    for (int dw = -1; dw <= 1; ++dw) {
      const int w2 = ww + dw;
      if ((unsigned)w2 >= 128u) continue;
      m = fmaxf(m, cb[(h2 << 7) + w2]);
    }
  }
  const bool alive = (premask[p] != 0.f) && (m > 0.1f);
  if (!alive) {
    float4 z; z.x = 0.f; z.y = 0.f; z.z = 0.f; z.w = 0.f;
    float* dst = xs + ((size_t)p << 4);
    *(float4*)(dst)      = z;
    *(float4*)(dst + 4)  = z;
    *(float4*)(dst + 8)  = z;
    *(float4*)(dst + 12) = z;
  }
}

// Pack per-neuron rows: [w0 row(48) | w1t(16) | b0 | pad3] stride 68.
__global__ void pack_weights(const float* __restrict__ w0,
                             const float* __restrict__ b0,
                             const float* __restrict__ w1,
                             float* __restrict__ pw) {
  const int j = blockIdx.x * 256 + threadIdx.x;
  if (j < 256) {
    float* r = pw + j * 68;
#pragma unroll
    for (int k = 0; k < 48; ++k) r[k] = w0[j * 48 + k];
#pragma unroll
    for (int c = 0; c < 16; ++c) r[48 + c] = w1[c * 256 + j];
    r[64] = b0[j];
    r[65] = 0.f; r[66] = 0.f; r[67] = 0.f;
  }
}

extern "C" void kernel_launch(void* const* d_in, const int* in_sizes, int n_in,
                              void* d_out, int out_size, void* d_ws, size_t ws_size,
                              hipStream_t stream) {
  const float* x0  = (const float*)d_in[0];
  const float* w0  = (const float*)d_in[1];
  const float* b0  = (const float*)d_in[2];
  const float* w1  = (const float*)d_in[3];
  const float* wfr = (const float*)d_in[4];
  const int steps = 4;

  float* xsteps  = (float*)d_out;
  float* frsteps = xsteps + (size_t)steps * XSLICE;

  float* pw  = (float*)d_ws;        // 256*68 = 17408 f
  float* ch3 = pw + 17408;          // BHW f
  float* pre = ch3 + BHW;           // BHW f

  // step keys = jax.random.split(jax.random.key(42), 4) (partitionable threefry)
  uint32_t sk[4][2];
  for (int s = 0; s < steps; ++s)
    tf2x32(0u, 42u, 0u, (uint32_t)s, sk[s][0], sk[s][1]);

  pack_weights<<<1, 256, 0, stream>>>(w0, b0, w1, pw);
  for (int s = 0; s < steps; ++s) {
    const float* xin = (s == 0) ? x0 : (xsteps + (size_t)(s - 1) * XSLICE);
    float* xmid = xsteps + (size_t)s * XSLICE;
    ca_step_a<<<512, 256, 0, stream>>>(xin, pw, wfr, xmid, ch3, pre,
                                       frsteps + (size_t)s * BHW, sk[s][0], sk[s][1]);
    ca_step_b<<<1024, 256, 0, stream>>>(xmid, ch3, pre);
  }
}